// Round 12
// baseline (159.898 us; speedup 1.0000x reference)
//
#include <hip/hip_runtime.h>
#include <stdint.h>

#define BB 4
#define CC 64
#define HH 64
#define WW 192
#define DD 24
#define HWQ (HH * WW)            // 12288 pixels per image plane
#define PIX (BB * HWQ)           // 49152 pixels per volume side

typedef __attribute__((ext_vector_type(8))) short short8;
typedef __attribute__((ext_vector_type(4))) float floatx4;

// ---------- bf16 helpers ----------
__device__ __forceinline__ float bf1(uint16_t u) {
    union { uint32_t i; float f; } c; c.i = ((uint32_t)u) << 16; return c.f;
}
__device__ __forceinline__ uint16_t f2bf(float f) {  // RNE, finite inputs only
    union { float f; uint32_t i; } c; c.f = f;
    uint32_t u = c.i;
    return (uint16_t)((u + 0x7fffu + ((u >> 16) & 1u)) >> 16);
}

// ws layout (shorts from base):
//   A: [2][PIX][CC] bf16; then f32 region: G[4096], beta[64], alpha[64],
//   gamma[1], pad, s[2*PIX] at f32 idx 4240.
#define A_SHORTS ((size_t)2 * PIX * CC)
#define S_F32OFF 4240

// =====================================================================
// Prep (parallel): blocks 0..63: G[i][j] = sum_c qw[c,i]*kw[c,j]
// block 64: beta[j] = sum_c qb[c]*kw[c,j] (+gamma on t0); block 65: alpha.
// grid 66, block 64.
// =====================================================================
__global__ __launch_bounds__(64) void prep_kernel(
    const float* __restrict__ qw, const float* __restrict__ qb,
    const float* __restrict__ kw, const float* __restrict__ kb,
    float* __restrict__ fws) {
    const int bid = blockIdx.x;
    const int j   = threadIdx.x;
    if (bid < 64) {
        float acc = 0.f;
        for (int c = 0; c < CC; c++)
            acc = fmaf(qw[c * CC + bid], kw[c * CC + j], acc);  // qw read wave-uniform
        fws[bid * 64 + j] = acc;
    } else if (bid == 64) {
        float bt = 0.f;
        for (int c = 0; c < CC; c++) bt = fmaf(qb[c], kw[c * CC + j], bt);
        fws[4096 + j] = bt;
        if (j == 0) {
            float g = 0.f;
            for (int c = 0; c < CC; c++) g = fmaf(qb[c], kb[c], g);
            fws[4224] = g;
        }
    } else {
        float al = 0.f;
        for (int c = 0; c < CC; c++) al = fmaf(qw[c * CC + j], kb[c], al);
        fws[4160 + j] = al;
    }
}

// =====================================================================
// convA (MFMA): A[v][pix][j] = bf16( X_pix . G[:,j] + beta[j] ),
//               s[v][pix]    = alpha . X_pix + gamma   (f32)
// X staged to LDS as bf16 [pix][c] (stride 70); G transposed to LDS
// [j][c] (stride 70). 8 m-tiles x 4 n-tiles = 32 MFMA tiles / 2 waves.
// grid (PIX/128, 2), block 128.
// =====================================================================
__global__ __launch_bounds__(128) void convA_kernel(
    const float* __restrict__ x, const float* __restrict__ y,
    const float* __restrict__ fws, uint16_t* __restrict__ A) {
    const int v = blockIdx.y;
    const float* src = v ? y : x;
    float* s = const_cast<float*>(fws) + S_F32OFF;

    __shared__ uint16_t Xt[128 * 70];   // 17,920 B  [pix][c]
    __shared__ uint16_t Gt[64 * 70];    //  8,960 B  [j][c]  (= G transposed)
    __shared__ float    bsS[64], alS[64];
    __shared__ float    gmS;

    const int tid  = threadIdx.x;
    const int pix0 = blockIdx.x * 128;
    const int b    = pix0 / HWQ;        // 96 blocks per plane: b uniform
    const int hw0  = pix0 - b * HWQ;

    // ---- stage G transposed + bias/alpha/gamma ----
    for (int idx = tid; idx < 4096; idx += 128) {
        const int c = idx >> 6, j = idx & 63;
        Gt[j * 70 + c] = f2bf(fws[idx]);
    }
    if (tid < 64) { bsS[tid] = fws[4096 + tid]; alS[tid] = fws[4160 + tid]; }
    if (tid == 64) gmS = fws[4224];

    // ---- stage Xt: (c-pair, pixel-group-of-4); coalesced float4 loads ----
    const float* sp = src + (size_t)b * CC * HWQ + hw0;
    for (int it = tid; it < 1024; it += 128) {
        const int pg = it & 31;          // pixel group (lane-major -> coalesced)
        const int cp = it >> 5;          // c-pair 0..31
        float4 r0 = *reinterpret_cast<const float4*>(sp + (size_t)(2 * cp)     * HWQ + pg * 4);
        float4 r1 = *reinterpret_cast<const float4*>(sp + (size_t)(2 * cp + 1) * HWQ + pg * 4);
        const int base = (pg * 4) * 70 + 2 * cp;   // u16 idx, dword aligned
        *reinterpret_cast<uint32_t*>(&Xt[base])           = (uint32_t)f2bf(r0.x) | ((uint32_t)f2bf(r1.x) << 16);
        *reinterpret_cast<uint32_t*>(&Xt[base + 70])      = (uint32_t)f2bf(r0.y) | ((uint32_t)f2bf(r1.y) << 16);
        *reinterpret_cast<uint32_t*>(&Xt[base + 140])     = (uint32_t)f2bf(r0.z) | ((uint32_t)f2bf(r1.z) << 16);
        *reinterpret_cast<uint32_t*>(&Xt[base + 210])     = (uint32_t)f2bf(r0.w) | ((uint32_t)f2bf(r1.w) << 16);
    }
    __syncthreads();

    const int wave = tid >> 6;
    const int lane = tid & 63;
    const int lq   = lane >> 4;
    const int ln   = lane & 15;

    uint16_t* Abase = A + (size_t)v * PIX * CC;
    // ---- MFMA: 32 tiles (8 m x 4 n), 16 per wave ----
    for (int t = wave * 16; t < wave * 16 + 16; t++) {
        const int mt = t >> 2, nt = t & 3;
        const uint16_t* xr = &Xt[(mt * 16 + ln) * 70 + lq * 8];
        const uint16_t* gr = &Gt[(nt * 16 + ln) * 70 + lq * 8];
        short8 a0, a1, b0, b1;
        *reinterpret_cast<uint2*>(&a0)       = *reinterpret_cast<const uint2*>(xr);
        *(reinterpret_cast<uint2*>(&a0) + 1) = *reinterpret_cast<const uint2*>(xr + 4);
        *reinterpret_cast<uint2*>(&a1)       = *reinterpret_cast<const uint2*>(xr + 32);
        *(reinterpret_cast<uint2*>(&a1) + 1) = *reinterpret_cast<const uint2*>(xr + 36);
        *reinterpret_cast<uint2*>(&b0)       = *reinterpret_cast<const uint2*>(gr);
        *(reinterpret_cast<uint2*>(&b0) + 1) = *reinterpret_cast<const uint2*>(gr + 4);
        *reinterpret_cast<uint2*>(&b1)       = *reinterpret_cast<const uint2*>(gr + 32);
        *(reinterpret_cast<uint2*>(&b1) + 1) = *reinterpret_cast<const uint2*>(gr + 36);
        const float bias = bsS[nt * 16 + ln];
        floatx4 acc = {bias, bias, bias, bias};
        acc = __builtin_amdgcn_mfma_f32_16x16x32_bf16(a0, b0, acc, 0, 0, 0);
        acc = __builtin_amdgcn_mfma_f32_16x16x32_bf16(a1, b1, acc, 0, 0, 0);
        // C: col(N)=ln -> j ; row(M)=lq*4+reg -> pixel
        uint16_t* dp = Abase + (size_t)(pix0 + mt * 16 + lq * 4) * CC + nt * 16 + ln;
        dp[0 * CC] = f2bf(acc[0]);
        dp[1 * CC] = f2bf(acc[1]);
        dp[2 * CC] = f2bf(acc[2]);
        dp[3 * CC] = f2bf(acc[3]);
    }

    // ---- s-phase: one pixel per thread from LDS ----
    {
        float sacc = gmS;
        const uint16_t* xp = &Xt[tid * 70];
        for (int c = 0; c < CC; c++) sacc = fmaf(alS[c], bf1(xp[c]), sacc);
        s[(size_t)v * PIX + pix0 + tid] = sacc;
    }
}

// =====================================================================
// Cost: ONE block per (h, b, v), 1024 threads (16 waves). Stage the
// bilinear-combined Y row ONCE: Yc[x][c] = bf16(ey0*Y[y0c] + ey1*Y[y1c]),
// stride 70 (conflict-free). Two 96-w halves: 72 MFMA tiles flat over 16
// waves -> Pt (stride 198), barrier, epilogue. LDS 64,896 B -> 2 blocks/CU.
// grid (HH, BB, 2), block 1024.
// =====================================================================
__global__ __launch_bounds__(1024) void cost_kernel(
    const float* __restrict__ x, const float* __restrict__ y,
    const float* __restrict__ disp1, const float* __restrict__ disp2,
    const uint16_t* __restrict__ A, const float* __restrict__ fws,
    float* __restrict__ out) {
    const int h = blockIdx.x;
    const int b = blockIdx.y;
    const int v = blockIdx.z;

    const float*    Yv   = v ? x : y;          // gathered (raw) source
    const float*    disp = v ? disp2 : disp1;
    const uint16_t* Ab   = A + ((size_t)v * PIX + (size_t)b * HWQ + h * WW) * CC;
    const float*    sb   = fws + S_F32OFF + (size_t)v * PIX + (size_t)b * HWQ + h * WW;

    // ---- row geometry (uniform) ----
    const float ys  = (float)h * (float)(64.0 / 63.0) - 0.5f;
    const float y0f = floorf(ys);
    const float ty  = ys - y0f;
    const int   y0  = (int)y0f;
    const int   y1  = y0 + 1;
    const float vy0 = (y0 >= 0 && y0 < HH) ? 1.f : 0.f;
    const float vy1 = (y1 >= 0 && y1 < HH) ? 1.f : 0.f;
    const int   y0c = min(max(y0, 0), HH - 1);
    const int   y1c = min(max(y1, 0), HH - 1);
    const float ey0 = (1.f - ty) * vy0;
    const float ey1 = ty * vy1;
    const float eysum = ey0 + ey1;

    __shared__ uint16_t Yc[192 * 70];   // 26,880 B: combined row, [x][c]
    __shared__ uint16_t Pt[96 * 198];   // 38,016 B: [w_half_local][x]

    const int tid  = threadIdx.x;
    const int wave = tid >> 6;
    const int lane = tid & 63;
    const int lq   = lane >> 4;
    const int ln   = lane & 15;

    // ---- stage Yc once: wave = c-group (16 groups of 4c), x = k*64+lane ----
    const float* Yb0 = Yv + ((size_t)b * CC * HH + y0c) * WW;
    const float* Yb1 = Yv + ((size_t)b * CC * HH + y1c) * WW;
#pragma unroll
    for (int k = 0; k < 3; k++) {
        const int cg = wave;
        const int xx = k * 64 + lane;
        uint32_t pk[2];
#pragma unroll
        for (int half = 0; half < 2; half++) {
            uint32_t pv = 0;
#pragma unroll
            for (int j = 0; j < 2; j++) {
                const int c = cg * 4 + half * 2 + j;
                const float v0 = Yb0[(size_t)c * HH * WW + xx];
                const float v1 = Yb1[(size_t)c * HH * WW + xx];
                const float cb = fmaf(ey1, v1, ey0 * v0);
                pv |= ((uint32_t)f2bf(cb)) << (16 * j);
            }
            pk[half] = pv;
        }
        *reinterpret_cast<uint2*>(&Yc[xx * 70 + cg * 4]) = *reinterpret_cast<uint2*>(pk);
    }
    __syncthreads();

    const float cx = (float)(192.0 / 191.0);
    const float inv_c = 1.f / 64.f;

    for (int half = 0; half < 2; half++) {
        // ---- MFMA: 6 m-chunks x 12 n-tiles = 72 tiles flat over 16 waves ----
        for (int t = wave; t < 72; t += 16) {
            const int mcl = t / 12;
            const int nt  = t - mcl * 12;
            const uint16_t* ar = Ab + (size_t)(half * 96 + mcl * 16 + ln) * CC + lq * 8;
            short8 a0 = *reinterpret_cast<const short8*>(ar);
            short8 a1 = *reinterpret_cast<const short8*>(ar + 32);
            const int Rb = nt * 16;
            const uint16_t* yrow = &Yc[(Rb + ln) * 70 + lq * 8];
            short8 b0, b1;
            *reinterpret_cast<uint2*>(&b0)       = *reinterpret_cast<const uint2*>(yrow);
            *(reinterpret_cast<uint2*>(&b0) + 1) = *reinterpret_cast<const uint2*>(yrow + 4);
            *reinterpret_cast<uint2*>(&b1)       = *reinterpret_cast<const uint2*>(yrow + 32);
            *(reinterpret_cast<uint2*>(&b1) + 1) = *reinterpret_cast<const uint2*>(yrow + 36);
            floatx4 acc = {0.f, 0.f, 0.f, 0.f};
            acc = __builtin_amdgcn_mfma_f32_16x16x32_bf16(a0, b0, acc, 0, 0, 0);
            acc = __builtin_amdgcn_mfma_f32_16x16x32_bf16(a1, b1, acc, 0, 0, 0);
            // C: col(N)=ln -> x' ; row(M)=lq*4+reg -> w_local
            const int pcol = Rb + ln;
            const int wl   = mcl * 16 + lq * 4;
            Pt[(wl + 0) * 198 + pcol] = f2bf(acc[0]);
            Pt[(wl + 1) * 198 + pcol] = f2bf(acc[1]);
            Pt[(wl + 2) * 198 + pcol] = f2bf(acc[2]);
            Pt[(wl + 3) * 198 + pcol] = f2bf(acc[3]);
        }
        __syncthreads();

        // ---- epilogue: 96 w x 24 d outputs ----
        for (int o = tid; o < 96 * DD; o += 1024) {
            const int wl = o % 96;           // local w within half
            const int d  = o / 96;
            const int w  = half * 96 + wl;
            const float dsv = disp[((size_t)(b * DD + d) * HH + h) * WW + w];
            const float xs  = dsv * cx - 0.5f;
            const float x0f = floorf(xs);
            const float tx  = xs - x0f;
            const int   x0  = (int)x0f;
            const int   x1  = x0 + 1;
            const float vx0 = (x0 >= 0 && x0 < WW) ? 1.f : 0.f;
            const float vx1 = (x1 >= 0 && x1 < WW) ? 1.f : 0.f;
            const int   x0c = min(max(x0, 0), WW - 1);
            const int   x1c = min(max(x1, 0), WW - 1);
            const float wx0 = (1.f - tx) * vx0;
            const float wx1 = tx * vx1;
            const float pc0 = bf1(Pt[wl * 198 + x0c]);
            const float pc1 = bf1(Pt[wl * 198 + x1c]);
            const float res = wx0 * pc0 + wx1 * pc1 + sb[w] * (eysum * (wx0 + wx1));
            out[(((size_t)(v * BB + b) * DD + d) * HH + h) * WW + w] = res * inv_c;
        }
        if (half == 0) __syncthreads();   // protect Pt before half-1 MFMA writes
    }
}

// =====================================================================
extern "C" void kernel_launch(void* const* d_in, const int* in_sizes, int n_in,
                              void* d_out, int out_size, void* d_ws, size_t ws_size,
                              hipStream_t stream) {
    const float* x  = (const float*)d_in[0];
    const float* y  = (const float*)d_in[1];
    const float* d1 = (const float*)d_in[2];
    const float* d2 = (const float*)d_in[3];
    // d_in[4] = ndisp (int32) — compile-time DD=24
    const float* qw = (const float*)d_in[5];
    const float* qb = (const float*)d_in[6];
    const float* kw = (const float*)d_in[7];
    const float* kb = (const float*)d_in[8];

    uint16_t* A   = (uint16_t*)d_ws;
    float*    fws = (float*)((uint16_t*)d_ws + A_SHORTS);
    float*    out = (float*)d_out;

    prep_kernel<<<dim3(66), dim3(64), 0, stream>>>(qw, qb, kw, kb, fws);
    convA_kernel<<<dim3(PIX / 128, 2), dim3(128), 0, stream>>>(x, y, fws, A);
    cost_kernel<<<dim3(HH, BB, 2), dim3(1024), 0, stream>>>(x, y, d1, d2, A, fws, out);
}

// Round 13
// 125.777 us; speedup vs baseline: 1.2713x; 1.2713x over previous
//
#include <hip/hip_runtime.h>
#include <stdint.h>

#define BB 4
#define CC 64
#define HH 64
#define WW 192
#define DD 24
#define HWQ (HH * WW)            // 12288 pixels per image plane
#define PIX (BB * HWQ)           // 49152 pixels per volume side

typedef __attribute__((ext_vector_type(8))) short short8;
typedef __attribute__((ext_vector_type(4))) float floatx4;

// ---------- bf16 helpers ----------
__device__ __forceinline__ float bf1(uint16_t u) {
    union { uint32_t i; float f; } c; c.i = ((uint32_t)u) << 16; return c.f;
}
__device__ __forceinline__ uint16_t f2bf(float f) {  // RNE, finite inputs only
    union { float f; uint32_t i; } c; c.f = f;
    uint32_t u = c.i;
    return (uint16_t)((u + 0x7fffu + ((u >> 16) & 1u)) >> 16);
}

// ws layout (shorts from base):
//   A:   [2][PIX][CC] bf16                       (6,291,456 shorts)
//   Ybf: [2][BB][CC][HH][WW] bf16 mirror of x,y  (6,291,456 shorts)
//   f32 region: G[4096], beta[64], alpha[64], gamma[1], pad, s[2*PIX] @4240.
#define A_SHORTS ((size_t)2 * PIX * CC)
#define S_F32OFF 4240

// =====================================================================
// Prep (parallel): blocks 0..63: G[i][j] = sum_c qw[c,i]*kw[c,j]
// block 64: beta[j] = sum_c qb[c]*kw[c,j] (+gamma on t0); block 65: alpha.
// grid 66, block 64.
// =====================================================================
__global__ __launch_bounds__(64) void prep_kernel(
    const float* __restrict__ qw, const float* __restrict__ qb,
    const float* __restrict__ kw, const float* __restrict__ kb,
    float* __restrict__ fws) {
    const int bid = blockIdx.x;
    const int j   = threadIdx.x;
    if (bid < 64) {
        float acc = 0.f;
        for (int c = 0; c < CC; c++)
            acc = fmaf(qw[c * CC + bid], kw[c * CC + j], acc);  // qw read wave-uniform
        fws[bid * 64 + j] = acc;
    } else if (bid == 64) {
        float bt = 0.f;
        for (int c = 0; c < CC; c++) bt = fmaf(qb[c], kw[c * CC + j], bt);
        fws[4096 + j] = bt;
        if (j == 0) {
            float g = 0.f;
            for (int c = 0; c < CC; c++) g = fmaf(qb[c], kb[c], g);
            fws[4224] = g;
        }
    } else {
        float al = 0.f;
        for (int c = 0; c < CC; c++) al = fmaf(qw[c * CC + j], kb[c], al);
        fws[4160 + j] = al;
    }
}

// =====================================================================
// convA (VALU, proven R11 structure): A[v][pix][j] = bf16(X.G[:,j]+beta[j]),
// s[v][pix] = alpha.X + gamma. NEW: emits bf16 mirror Ybf[v] of its source
// (each wave writes channels i%4==wave; coalesced 8B stores).
// grid (PIX/256, 2), block (64,4).
// =====================================================================
__global__ __launch_bounds__(256) void convA_kernel(
    const float* __restrict__ x, const float* __restrict__ y,
    const float* __restrict__ fws, uint16_t* __restrict__ A,
    uint16_t* __restrict__ Ybf) {
    const int v = blockIdx.y;
    const float* src = v ? y : x;
    float* s = const_cast<float*>(fws) + S_F32OFF;

    __shared__ float wt[64][64];   // wt[i][j] = G[i][j]
    __shared__ float bs[64], al[64];
    __shared__ float gm;
    const int tid = threadIdx.y * 64 + threadIdx.x;
    for (int idx = tid; idx < 4096; idx += 256) wt[idx >> 6][idx & 63] = fws[idx];
    if (tid < 64) { bs[tid] = fws[4096 + tid]; al[tid] = fws[4160 + tid]; }
    if (tid == 64) gm = fws[4224];
    __syncthreads();

    const int pix0 = blockIdx.x * 256 + threadIdx.x * 4;
    const int b    = pix0 / HWQ;
    const int hw0  = pix0 - b * HWQ;
    const int j0   = threadIdx.y * 16;

    float acc[4][16];
#pragma unroll
    for (int p = 0; p < 4; p++)
#pragma unroll
        for (int k = 0; k < 16; k++) acc[p][k] = bs[j0 + k];
    float sac[4] = {gm, gm, gm, gm};

    const float*    sp   = src + (size_t)b * CC * HWQ + hw0;
    uint16_t*       Ymir = Ybf + (size_t)v * PIX * CC + (size_t)b * CC * HWQ + hw0;
#pragma unroll 4
    for (int i = 0; i < 64; i++) {
        float4 raw = *reinterpret_cast<const float4*>(sp + (size_t)i * HWQ);
        if ((i & 3) == threadIdx.y) {   // wave-uniform: this wave mirrors channel i
            uint2 pv;
            pv.x = (uint32_t)f2bf(raw.x) | ((uint32_t)f2bf(raw.y) << 16);
            pv.y = (uint32_t)f2bf(raw.z) | ((uint32_t)f2bf(raw.w) << 16);
            *reinterpret_cast<uint2*>(Ymir + (size_t)i * HWQ) = pv;
        }
        const float* wr = &wt[i][j0];   // wave-uniform -> LDS broadcast
        const float av = al[i];
        sac[0] = fmaf(raw.x, av, sac[0]);
        sac[1] = fmaf(raw.y, av, sac[1]);
        sac[2] = fmaf(raw.z, av, sac[2]);
        sac[3] = fmaf(raw.w, av, sac[3]);
#pragma unroll
        for (int k = 0; k < 16; k++) {
            float wv = wr[k];
            acc[0][k] = fmaf(raw.x, wv, acc[0][k]);
            acc[1][k] = fmaf(raw.y, wv, acc[1][k]);
            acc[2][k] = fmaf(raw.z, wv, acc[2][k]);
            acc[3][k] = fmaf(raw.w, wv, acc[3][k]);
        }
    }

    uint16_t* dstv = A + (size_t)v * PIX * CC;
#pragma unroll
    for (int p = 0; p < 4; p++) {
        uint32_t pk[8];
#pragma unroll
        for (int k = 0; k < 8; k++)
            pk[k] = (uint32_t)f2bf(acc[p][2 * k]) | ((uint32_t)f2bf(acc[p][2 * k + 1]) << 16);
        uint16_t* dp = dstv + (size_t)(pix0 + p) * CC + j0;
        uint4 lo; lo.x = pk[0]; lo.y = pk[1]; lo.z = pk[2]; lo.w = pk[3];
        uint4 hi; hi.x = pk[4]; hi.y = pk[5]; hi.z = pk[6]; hi.w = pk[7];
        *reinterpret_cast<uint4*>(dp)     = lo;
        *reinterpret_cast<uint4*>(dp + 8) = hi;
    }
    if (threadIdx.y == 0) {
        float4 sv; sv.x = sac[0]; sv.y = sac[1]; sv.z = sac[2]; sv.w = sac[3];
        *reinterpret_cast<float4*>(s + (size_t)v * PIX + pix0) = sv;
    }
}

// =====================================================================
// Cost (R11 structure): ONE block per (h, b, v), 1024 threads. Stage the
// bilinear-combined Y row ONCE from the bf16 mirror (half the bytes of R11):
// Yc[x][c] = bf16(ey0*Ybf[y0c] + ey1*Ybf[y1c]), stride 68. Two 96-w halves:
// waves 0..11, one A-frag load per wave per half reused by 6 MFMA tiles
// -> Pt (stride 196), barrier, epilogue. LDS 63.7 KB -> 2 blocks/CU.
// grid (HH, BB, 2), block 1024.
// =====================================================================
__global__ __launch_bounds__(1024) void cost_kernel(
    const float* __restrict__ disp1, const float* __restrict__ disp2,
    const uint16_t* __restrict__ A, const uint16_t* __restrict__ Ybf,
    const float* __restrict__ fws, float* __restrict__ out) {
    const int h = blockIdx.x;
    const int b = blockIdx.y;
    const int v = blockIdx.z;

    const int       tsel = v ? 0 : 1;          // v=0 gathers y (=Ybf[1]), v=1 gathers x (=Ybf[0])
    const float*    disp = v ? disp2 : disp1;
    const uint16_t* Ab   = A + ((size_t)v * PIX + (size_t)b * HWQ + h * WW) * CC;
    const float*    sb   = fws + S_F32OFF + (size_t)v * PIX + (size_t)b * HWQ + h * WW;

    // ---- row geometry (uniform) ----
    const float ys  = (float)h * (float)(64.0 / 63.0) - 0.5f;
    const float y0f = floorf(ys);
    const float ty  = ys - y0f;
    const int   y0  = (int)y0f;
    const int   y1  = y0 + 1;
    const float vy0 = (y0 >= 0 && y0 < HH) ? 1.f : 0.f;
    const float vy1 = (y1 >= 0 && y1 < HH) ? 1.f : 0.f;
    const int   y0c = min(max(y0, 0), HH - 1);
    const int   y1c = min(max(y1, 0), HH - 1);
    const float ey0 = (1.f - ty) * vy0;
    const float ey1 = ty * vy1;
    const float eysum = ey0 + ey1;

    __shared__ uint16_t Yc[192 * 68];   // 26,112 B: combined row, [x][c]
    __shared__ uint16_t Pt[96 * 196];   // 37,632 B: [w_half_local][x]

    const int tid  = threadIdx.x;
    const int wave = tid >> 6;
    const int lane = tid & 63;
    const int lq   = lane >> 4;
    const int ln   = lane & 63 & 0xF;   // lane & 15

    // ---- stage Yc once from bf16 mirror: wave = c-group, x = k*64+lane ----
    const uint16_t* Yb0 = Ybf + (size_t)tsel * PIX * CC + (size_t)b * CC * HWQ + y0c * WW;
    const uint16_t* Yb1 = Ybf + (size_t)tsel * PIX * CC + (size_t)b * CC * HWQ + y1c * WW;
#pragma unroll
    for (int k = 0; k < 3; k++) {
        const int cg = wave;
        const int xx = k * 64 + lane;
        uint32_t pk[2];
#pragma unroll
        for (int half = 0; half < 2; half++) {
            uint32_t pv = 0;
#pragma unroll
            for (int j = 0; j < 2; j++) {
                const int c = cg * 4 + half * 2 + j;
                const float v0 = bf1(Yb0[(size_t)c * HWQ + xx]);
                const float v1 = bf1(Yb1[(size_t)c * HWQ + xx]);
                const float cb = fmaf(ey1, v1, ey0 * v0);
                pv |= ((uint32_t)f2bf(cb)) << (16 * j);
            }
            pk[half] = pv;
        }
        *reinterpret_cast<uint2*>(&Yc[xx * 68 + cg * 4]) = *reinterpret_cast<uint2*>(pk);
    }
    __syncthreads();

    const float cx = (float)(192.0 / 191.0);
    const float inv_c = 1.f / 64.f;

    for (int half = 0; half < 2; half++) {
        // ---- MFMA: 6 m-chunks x 12 n-tiles; waves 0..11, A-frag reused x6 ----
        if (wave < 12) {
            const int mcl = wave >> 1;                    // local m-chunk 0..5
            const uint16_t* ar = Ab + (size_t)(half * 96 + mcl * 16 + ln) * CC + lq * 8;
            short8 a0 = *reinterpret_cast<const short8*>(ar);
            short8 a1 = *reinterpret_cast<const short8*>(ar + 32);
#pragma unroll
            for (int i = 0; i < 6; i++) {
                const int nt = (wave & 1) * 6 + i;
                const int Rb = nt * 16;
                const uint16_t* yrow = &Yc[(Rb + ln) * 68 + lq * 8];
                short8 b0, b1;
                *reinterpret_cast<uint2*>(&b0)       = *reinterpret_cast<const uint2*>(yrow);
                *(reinterpret_cast<uint2*>(&b0) + 1) = *reinterpret_cast<const uint2*>(yrow + 4);
                *reinterpret_cast<uint2*>(&b1)       = *reinterpret_cast<const uint2*>(yrow + 32);
                *(reinterpret_cast<uint2*>(&b1) + 1) = *reinterpret_cast<const uint2*>(yrow + 36);
                floatx4 acc = {0.f, 0.f, 0.f, 0.f};
                acc = __builtin_amdgcn_mfma_f32_16x16x32_bf16(a0, b0, acc, 0, 0, 0);
                acc = __builtin_amdgcn_mfma_f32_16x16x32_bf16(a1, b1, acc, 0, 0, 0);
                // C: col(N)=ln -> x' ; row(M)=lq*4+reg -> w_local
                const int pcol = Rb + ln;
                const int wl   = mcl * 16 + lq * 4;
                Pt[(wl + 0) * 196 + pcol] = f2bf(acc[0]);
                Pt[(wl + 1) * 196 + pcol] = f2bf(acc[1]);
                Pt[(wl + 2) * 196 + pcol] = f2bf(acc[2]);
                Pt[(wl + 3) * 196 + pcol] = f2bf(acc[3]);
            }
        }
        __syncthreads();

        // ---- epilogue: 96 w x 24 d outputs ----
        for (int o = tid; o < 96 * DD; o += 1024) {
            const int wl = o % 96;           // local w within half
            const int d  = o / 96;
            const int w  = half * 96 + wl;
            const float dsv = disp[((size_t)(b * DD + d) * HH + h) * WW + w];
            const float xs  = dsv * cx - 0.5f;
            const float x0f = floorf(xs);
            const float tx  = xs - x0f;
            const int   x0  = (int)x0f;
            const int   x1  = x0 + 1;
            const float vx0 = (x0 >= 0 && x0 < WW) ? 1.f : 0.f;
            const float vx1 = (x1 >= 0 && x1 < WW) ? 1.f : 0.f;
            const int   x0c = min(max(x0, 0), WW - 1);
            const int   x1c = min(max(x1, 0), WW - 1);
            const float wx0 = (1.f - tx) * vx0;
            const float wx1 = tx * vx1;
            const float pc0 = bf1(Pt[wl * 196 + x0c]);
            const float pc1 = bf1(Pt[wl * 196 + x1c]);
            const float res = wx0 * pc0 + wx1 * pc1 + sb[w] * (eysum * (wx0 + wx1));
            out[(((size_t)(v * BB + b) * DD + d) * HH + h) * WW + w] = res * inv_c;
        }
        if (half == 0) __syncthreads();   // protect Pt before half-1 MFMA writes
    }
}

// =====================================================================
extern "C" void kernel_launch(void* const* d_in, const int* in_sizes, int n_in,
                              void* d_out, int out_size, void* d_ws, size_t ws_size,
                              hipStream_t stream) {
    const float* x  = (const float*)d_in[0];
    const float* y  = (const float*)d_in[1];
    const float* d1 = (const float*)d_in[2];
    const float* d2 = (const float*)d_in[3];
    // d_in[4] = ndisp (int32) — compile-time DD=24
    const float* qw = (const float*)d_in[5];
    const float* qb = (const float*)d_in[6];
    const float* kw = (const float*)d_in[7];
    const float* kb = (const float*)d_in[8];

    uint16_t* A   = (uint16_t*)d_ws;
    uint16_t* Ybf = (uint16_t*)d_ws + A_SHORTS;
    float*    fws = (float*)((uint16_t*)d_ws + 2 * A_SHORTS);
    float*    out = (float*)d_out;

    prep_kernel<<<dim3(66), dim3(64), 0, stream>>>(qw, qb, kw, kb, fws);
    convA_kernel<<<dim3(PIX / 256, 2), dim3(64, 4), 0, stream>>>(x, y, fws, A, Ybf);
    cost_kernel<<<dim3(HH, BB, 2), dim3(1024), 0, stream>>>(d1, d2, A, Ybf, fws, out);
}